// Round 1
// baseline (234.833 us; speedup 1.0000x reference)
//
#include <hip/hip_runtime.h>

// Problem: B=2, H=32, S=8192, D=128, T=512, fp32.
// out = (updated_k, updated_v) concatenated flat: each B*H*S*D = 67,108,864 floats.

#define S_LEN 8192
#define T_LEN 512
#define D_DIM 128
#define BH    64            // B*H
#define ELEMS_PER_TENSOR (BH * S_LEN * D_DIM)      // 67,108,864
#define VECS_PER_TENSOR  (ELEMS_PER_TENSOR / 4)    // 16,777,216 float4s

// --- kernel 1: init inverse map to -1 -----------------------------------
__global__ void ssc_init_map(int* __restrict__ map) {
    int s = blockIdx.x * blockDim.x + threadIdx.x;
    if (s < S_LEN) map[s] = -1;
}

// --- kernel 2: scatter position_ids into the map ------------------------
// position_ids is arange(T) in the reference (int64 in jax). The harness may
// hand it to us as int32 or int64; detect which by range-checking the first
// two 8-byte reads (int32 data read as int64 puts element 1 in the high word,
// producing a value >= 2^32, out of [0,S) range).
__global__ void ssc_build_map(const void* __restrict__ pos, int* __restrict__ map) {
    int t = blockIdx.x * blockDim.x + threadIdx.x;
    if (t >= T_LEN) return;
    const long long* p64 = (const long long*)pos;
    const int*       p32 = (const int*)pos;
    long long a = p64[0], b = p64[1];
    bool is64 = (a >= 0) && (a < S_LEN) && (b >= 0) && (b < S_LEN) && (a != b);
    int s = is64 ? (int)p64[t] : p32[t];
    if (s >= 0 && s < S_LEN) map[s] = t;
}

// --- kernel 3: fused copy+scatter for K and V ---------------------------
// One float4 per (tensor-slot, iteration); K and V handled together so all
// index math is shared. idx layout: idx = ((bh*S + s)*(D/4) + d4).
__global__ __launch_bounds__(256) void ssc_scatter_copy(
    const float4* __restrict__ ck, const float4* __restrict__ cv,
    const float4* __restrict__ nk, const float4* __restrict__ nv,
    const int*    __restrict__ map,
    float4* __restrict__ ok, float4* __restrict__ ov) {
    const int stride = gridDim.x * blockDim.x;
    for (int idx = blockIdx.x * blockDim.x + threadIdx.x;
         idx < VECS_PER_TENSOR; idx += stride) {
        const int d4 = idx & 31;                 // D/4 = 32 vecs per row
        const int s  = (idx >> 5) & (S_LEN - 1); // seq row
        const int bh = idx >> 18;                // (b*H + h)
        const int t  = map[s];
        float4 kv, vv;
        if (t >= 0) {
            const int src = (bh * T_LEN + t) * (D_DIM / 4) + d4;
            kv = nk[src];
            vv = nv[src];
        } else {
            kv = ck[idx];
            vv = cv[idx];
        }
        ok[idx] = kv;
        ov[idx] = vv;
    }
}

extern "C" void kernel_launch(void* const* d_in, const int* in_sizes, int n_in,
                              void* d_out, int out_size, void* d_ws, size_t ws_size,
                              hipStream_t stream) {
    const float4* ck = (const float4*)d_in[0];
    const float4* cv = (const float4*)d_in[1];
    const float4* nk = (const float4*)d_in[2];
    const float4* nv = (const float4*)d_in[3];
    const void*   pos = d_in[4];

    float* out = (float*)d_out;
    float4* ok = (float4*)out;
    float4* ov = (float4*)(out + ELEMS_PER_TENSOR);

    int* map = (int*)d_ws;   // 8192 ints = 32 KiB scratch

    ssc_init_map<<<(S_LEN + 255) / 256, 256, 0, stream>>>(map);
    ssc_build_map<<<(T_LEN + 255) / 256, 256, 0, stream>>>(pos, map);
    ssc_scatter_copy<<<2048, 256, 0, stream>>>(ck, cv, nk, nv, map, ok, ov);
}

// Round 3
// 227.637 us; speedup vs baseline: 1.0316x; 1.0316x over previous
//
#include <hip/hip_runtime.h>

// Problem: B=2, H=32, S=8192, D=128, T=512, fp32.
// out = (updated_k, updated_v) concatenated flat: each B*H*S*D = 67,108,864 floats.

#define S_LEN 8192
#define T_LEN 512
#define D_DIM 128
#define BH    64            // B*H
#define ELEMS_PER_TENSOR (BH * S_LEN * D_DIM)      // 67,108,864 floats
#define VECS_PER_BH      (S_LEN * (D_DIM / 4))     // 262,144 float4s per bh slice
#define NEW_VECS_PER_BH  (T_LEN * (D_DIM / 4))     // 16,384 float4s per bh slice

// Native clang vector type — __builtin_nontemporal_* requires this, not
// HIP's HIP_vector_type<float,4>.
typedef float f4_t __attribute__((ext_vector_type(4)));

// --- kernel 1: build inverse map (init + scatter fused, single block) ----
// position_ids is arange(T) (int64 in jax). The harness may hand it to us as
// int32 or int64; detect by range-checking the first two 8-byte reads.
__global__ void ssc_build_map(const void* __restrict__ pos, int* __restrict__ map) {
    const int tid = threadIdx.x;
    for (int s = tid; s < S_LEN; s += 1024) map[s] = -1;
    __syncthreads();
    if (tid < T_LEN) {
        const long long* p64 = (const long long*)pos;
        const int*       p32 = (const int*)pos;
        long long a = p64[0], b = p64[1];
        bool is64 = (a >= 0) && (a < S_LEN) && (b >= 0) && (b < S_LEN) && (a != b);
        int s = is64 ? (int)p64[tid] : p32[tid];
        if (s >= 0 && s < S_LEN) map[s] = tid;
    }
}

// --- kernel 2: fused copy+scatter for K and V ---------------------------
// Each thread owns a fixed (s, d4): map lookup + branch hoisted out of the
// bh loop. Inner loop = pure streaming dwordx4, unrolled for ILP.
// gridDim = (1024, 2): blockIdx.y splits the 64 bh slices into 2 halves.
__global__ __launch_bounds__(256) void ssc_scatter_copy(
    const f4_t* __restrict__ ck, const f4_t* __restrict__ cv,
    const f4_t* __restrict__ nk, const f4_t* __restrict__ nv,
    const int*  __restrict__ map,
    f4_t* __restrict__ ok, f4_t* __restrict__ ov) {
    const int tid = blockIdx.x * 256 + threadIdx.x;   // 0 .. 262143
    const int d4  = tid & 31;                         // 32 float4s per row
    const int s   = tid >> 5;                         // 0 .. 8191
    const int t   = map[s];

    const int bh0    = blockIdx.y * (BH / 2);
    const int dstOff = s * 32 + d4;                   // vec index at bh=0

    if (t >= 0) {
        const int srcOff = t * 32 + d4;
        #pragma unroll 8
        for (int i = 0; i < BH / 2; ++i) {
            const int bh = bh0 + i;
            f4_t kv = __builtin_nontemporal_load(nk + srcOff + bh * NEW_VECS_PER_BH);
            f4_t vv = __builtin_nontemporal_load(nv + srcOff + bh * NEW_VECS_PER_BH);
            __builtin_nontemporal_store(kv, ok + dstOff + bh * VECS_PER_BH);
            __builtin_nontemporal_store(vv, ov + dstOff + bh * VECS_PER_BH);
        }
    } else {
        #pragma unroll 8
        for (int i = 0; i < BH / 2; ++i) {
            const int bh = bh0 + i;
            f4_t kv = __builtin_nontemporal_load(ck + dstOff + bh * VECS_PER_BH);
            f4_t vv = __builtin_nontemporal_load(cv + dstOff + bh * VECS_PER_BH);
            __builtin_nontemporal_store(kv, ok + dstOff + bh * VECS_PER_BH);
            __builtin_nontemporal_store(vv, ov + dstOff + bh * VECS_PER_BH);
        }
    }
}

extern "C" void kernel_launch(void* const* d_in, const int* in_sizes, int n_in,
                              void* d_out, int out_size, void* d_ws, size_t ws_size,
                              hipStream_t stream) {
    const f4_t* ck = (const f4_t*)d_in[0];
    const f4_t* cv = (const f4_t*)d_in[1];
    const f4_t* nk = (const f4_t*)d_in[2];
    const f4_t* nv = (const f4_t*)d_in[3];
    const void* pos = d_in[4];

    float* out = (float*)d_out;
    f4_t* ok = (f4_t*)out;
    f4_t* ov = (f4_t*)(out + ELEMS_PER_TENSOR);

    int* map = (int*)d_ws;   // 8192 ints = 32 KiB scratch

    ssc_build_map<<<1, 1024, 0, stream>>>(pos, map);
    ssc_scatter_copy<<<dim3(1024, 2), 256, 0, stream>>>(ck, cv, nk, nv, map, ok, ov);
}

// Round 4
// 199.729 us; speedup vs baseline: 1.1758x; 1.1397x over previous
//
#include <hip/hip_runtime.h>

// Problem: B=2, H=32, S=8192, D=128, T=512, fp32.
// out = (updated_k, updated_v) concatenated flat: each B*H*S*D = 67,108,864 floats.

#define S_LEN 8192
#define T_LEN 512
#define D_DIM 128
#define BH    64            // B*H
#define ELEMS_PER_TENSOR (BH * S_LEN * D_DIM)      // 67,108,864 floats
#define VECS_PER_BH      (S_LEN * (D_DIM / 4))     // 262,144 float4s per bh slice
#define NEW_VECS_PER_BH  (T_LEN * (D_DIM / 4))     // 16,384 float4s per bh slice

// Native clang vector type — __builtin_nontemporal_* requires this.
typedef float f4_t __attribute__((ext_vector_type(4)));

// --- single fused kernel -------------------------------------------------
// grid = (1024, 2, 2), block = 256.
//   blockIdx.x: which (s,d4) chunk — block covers 8 consecutive seq rows.
//   blockIdx.y: which half of the 64 bh slices.
//   blockIdx.z: 0 = K tensor, 1 = V tensor  (1 read + 1 write stream/thread,
//               the m13 copy-benchmark shape).
// The inverse position map is built PER BLOCK in LDS: the block only needs
// map[] for its 8 rows, so 256 threads scan the 512 positions (2 each).
__global__ __launch_bounds__(256) void ssc_fused(
    const f4_t* __restrict__ ck, const f4_t* __restrict__ cv,
    const f4_t* __restrict__ nk, const f4_t* __restrict__ nv,
    const void* __restrict__ pos,
    f4_t* __restrict__ ok, f4_t* __restrict__ ov) {

    __shared__ int lmap[8];
    const int ltid = threadIdx.x;
    const int s0   = blockIdx.x * 8;           // first seq row of this block

    if (ltid < 8) lmap[ltid] = -1;
    __syncthreads();

    // positions may arrive as int32 or int64; detect by range-checking the
    // first two 8-byte reads (int32 read as int64 misparses element 1).
    {
        const long long* p64 = (const long long*)pos;
        const int*       p32 = (const int*)pos;
        long long a = p64[0], b = p64[1];
        bool is64 = (a >= 0) && (a < S_LEN) && (b >= 0) && (b < S_LEN) && (a != b);
        #pragma unroll
        for (int j = ltid; j < T_LEN; j += 256) {
            int p = is64 ? (int)p64[j] : p32[j];
            unsigned r = (unsigned)(p - s0);
            if (r < 8u) lmap[r] = j;
        }
    }
    __syncthreads();

    const int tid = blockIdx.x * 256 + ltid;   // 0 .. 262143
    const int d4  = tid & 31;                  // 32 float4s per row
    const int s   = tid >> 5;                  // 0 .. 8191
    const int t   = lmap[s & 7];

    // pick tensor (wave-uniform)
    const f4_t* csrc = blockIdx.z ? cv : ck;
    const f4_t* nsrc = blockIdx.z ? nv : nk;
    f4_t*       odst = blockIdx.z ? ov : ok;

    const int bh0    = blockIdx.y * (BH / 2);
    const int dstOff = s * 32 + d4;            // vec index within a bh slice

    const f4_t* src;
    int sstride;
    if (t >= 0) { src = nsrc + (t * 32 + d4) + bh0 * NEW_VECS_PER_BH; sstride = NEW_VECS_PER_BH; }
    else        { src = csrc + dstOff          + bh0 * VECS_PER_BH;    sstride = VECS_PER_BH; }
    f4_t* dst = odst + dstOff + bh0 * VECS_PER_BH;

    #pragma unroll 4
    for (int i = 0; i < BH / 2; ++i) {
        f4_t v = __builtin_nontemporal_load(src);
        __builtin_nontemporal_store(v, dst);
        src += sstride;
        dst += VECS_PER_BH;
    }
}

extern "C" void kernel_launch(void* const* d_in, const int* in_sizes, int n_in,
                              void* d_out, int out_size, void* d_ws, size_t ws_size,
                              hipStream_t stream) {
    const f4_t* ck = (const f4_t*)d_in[0];
    const f4_t* cv = (const f4_t*)d_in[1];
    const f4_t* nk = (const f4_t*)d_in[2];
    const f4_t* nv = (const f4_t*)d_in[3];
    const void* pos = d_in[4];

    float* out = (float*)d_out;
    f4_t* ok = (f4_t*)out;
    f4_t* ov = (f4_t*)(out + ELEMS_PER_TENSOR);

    ssc_fused<<<dim3(1024, 2, 2), 256, 0, stream>>>(ck, cv, nk, nv, pos, ok, ov);
}